// Round 1
// baseline (653.928 us; speedup 1.0000x reference)
//
#include <hip/hip_runtime.h>
#include <math.h>

#define NN 20000
#define EE 320000

// ---------------- weight transpose: w[rows][cols] -> wt[cols][rows] ----------------
__global__ void k_transpose(const float* __restrict__ w, float* __restrict__ wt,
                            int rows, int cols) {
    int idx = blockIdx.x * 256 + threadIdx.x;
    if (idx < rows * cols) {
        int r = idx / cols, k = idx - r * cols;
        wt[k * rows + r] = w[idx];
    }
}

// ---------------- generic tiled GEMM: C = act(A @ Wt + b) ----------------
// A: [M,128] row-major. Wt: [128][ofld] (pre-transposed weight). 64x64 tile, 4x4/thread.
// DUAL: acc = A1@Wt1 + A2@Wt2 (+b1+b2)  (K=128 each) -- for GRU r/z gates.
// ACT: 0 none, 1 leaky_relu(0.2), 2 exact gelu.
template<int ACT, bool DUAL>
__global__ __launch_bounds__(256) void k_gemm(
    const float* __restrict__ A1, const float* __restrict__ A2,
    const float* __restrict__ Wt1, const float* __restrict__ Wt2,
    const float* __restrict__ b1, const float* __restrict__ b2,
    float* __restrict__ C, int M, int ofld, int ofStart, int cld, int cOut)
{
    __shared__ float As[64][132];   // 64 rows x 128 k (pad->132)
    __shared__ float Ws[64][68];    // 64 k-chunk x 64 cols (pad->68)
    const int tid = threadIdx.x;
    const int m0 = blockIdx.x * 64;
    const int colW = ofStart + blockIdx.y * 64;
    const int colC = cOut + blockIdx.y * 64;
    const int tc = tid & 15, tr = tid >> 4;
    const int c0 = tc * 4, r0 = tr * 4;
    float acc[4][4] = {};

    const int npass = DUAL ? 2 : 1;
    for (int pass = 0; pass < npass; pass++) {
        const float* __restrict__ Ap = pass ? A2 : A1;
        const float* __restrict__ Wp = pass ? Wt2 : Wt1;
        __syncthreads();
        {   // stage A tile (coalesced, zero-pad OOB rows)
            const int rb = tid >> 5;
            const int k4 = (tid & 31) * 4;
            #pragma unroll
            for (int i = 0; i < 8; i++) {
                const int rr = rb + i * 8;
                const int gm = m0 + rr;
                float4 v = make_float4(0.f, 0.f, 0.f, 0.f);
                if (gm < M) v = *(const float4*)(Ap + (size_t)gm * 128 + k4);
                *(float4*)&As[rr][k4] = v;
            }
        }
        #pragma unroll
        for (int kc = 0; kc < 2; kc++) {
            if (kc) __syncthreads();
            {   // stage W chunk
                const int kl = tid >> 4;
                const int c4 = (tid & 15) * 4;
                #pragma unroll
                for (int i = 0; i < 4; i++) {
                    const int kk = kl + i * 16;
                    *(float4*)&Ws[kk][c4] =
                        *(const float4*)(Wp + (size_t)(kc * 64 + kk) * ofld + colW + c4);
                }
            }
            __syncthreads();
            const int kb = kc * 64;
            #pragma unroll 4
            for (int k = 0; k < 64; k += 4) {
                float wk[4][4];
                #pragma unroll
                for (int q = 0; q < 4; q++)
                    *(float4*)wk[q] = *(const float4*)&Ws[k + q][c0];
                #pragma unroll
                for (int i = 0; i < 4; i++) {
                    float av[4];
                    *(float4*)av = *(const float4*)&As[r0 + i][kb + k];
                    #pragma unroll
                    for (int q = 0; q < 4; q++)
                        #pragma unroll
                        for (int j = 0; j < 4; j++)
                            acc[i][j] = fmaf(av[q], wk[q][j], acc[i][j]);
                }
            }
        }
    }

    float bb[4];
    *(float4*)bb = *(const float4*)(b1 + colW + c0);
    if (DUAL) {
        float bb2[4];
        *(float4*)bb2 = *(const float4*)(b2 + colW + c0);
        #pragma unroll
        for (int j = 0; j < 4; j++) bb[j] += bb2[j];
    }
    #pragma unroll
    for (int i = 0; i < 4; i++) {
        const int row = m0 + r0 + i;
        if (row < M) {
            float o[4];
            #pragma unroll
            for (int j = 0; j < 4; j++) {
                float v = acc[i][j] + bb[j];
                if (ACT == 1)      v = v > 0.f ? v : 0.2f * v;
                else if (ACT == 2) v = 0.5f * v * (1.f + erff(v * 0.70710678118654752f));
                o[j] = v;
            }
            *(float4*)(C + (size_t)row * cld + colC + c0) = *(float4*)o;
        }
    }
}

// ---------------- per-node dots with att vector(s) ----------------
// a[n] = dot(X[n], w[0:128]);  if TWO: b[n] = dot(X[n], w[128:256])
template<bool TWO>
__global__ void k_node_dots(const float* __restrict__ X, const float* __restrict__ w,
                            float* __restrict__ a, float* __restrict__ b)
{
    int n = blockIdx.x * 4 + (threadIdx.x >> 6);
    int l = threadIdx.x & 63;
    if (n >= NN) return;
    float x1 = X[(size_t)n * 128 + l], x2 = X[(size_t)n * 128 + l + 64];
    float s = x1 * w[l] + x2 * w[l + 64];
    float t = TWO ? (x1 * w[128 + l] + x2 * w[192 + l]) : 0.f;
    #pragma unroll
    for (int m = 32; m >= 1; m >>= 1) {
        s += __shfl_xor(s, m, 64);
        if (TWO) t += __shfl_xor(t, m, 64);
    }
    if (l == 0) { a[n] = s; if (TWO) b[n] = t; }
}

// ---------------- V1 edge logits: full E x 128 x 144 GEMM reduced to scalar/edge ----
// logit_e = lrelu( adst[dst] + att_b + sum_c attw[128+c]*lrelu( (W2 [atom[src];bond])_c + b2_c ) )
__global__ __launch_bounds__(256) void k_edge_logits_v1(
    const float* __restrict__ atom, const int* __restrict__ esrc,
    const float* __restrict__ bond, const float* __restrict__ W2t, // [144][128]
    const float* __restrict__ b2, const float* __restrict__ attw,  // att_w (256)
    const float* __restrict__ attb1, const float* __restrict__ adst,
    float* __restrict__ logits)
{
    __shared__ float Ain[64][148];  // 64 edges x 144 inputs (pad->148)
    const int tid = threadIdx.x;
    const int e0 = blockIdx.x * 64;
    {   // gather-stage inputs: [atom[src] (128) | bond (16)]
        int r = tid >> 2, t = tid & 3;
        int e = e0 + r;
        int src = esrc[e];
        const float* arow = atom + (size_t)src * 128;
        #pragma unroll
        for (int i = 0; i < 9; i++) {
            int f4 = t + i * 4;
            float4 v;
            if (f4 < 32) v = *(const float4*)&arow[f4 * 4];
            else         v = *(const float4*)&bond[(size_t)e * 16 + (f4 - 32) * 4];
            *(float4*)&Ain[r][f4 * 4] = v;
        }
    }
    __syncthreads();
    const int tc = tid & 31, tr = tid >> 5;
    const int c0 = tc * 4, r0 = tr * 8;
    float acc[8][4] = {};
    for (int k = 0; k < 144; k += 4) {
        float wk[4][4];
        #pragma unroll
        for (int q = 0; q < 4; q++)
            *(float4*)wk[q] = *(const float4*)&W2t[(size_t)(k + q) * 128 + c0];
        #pragma unroll
        for (int i = 0; i < 8; i++) {
            float av[4];
            *(float4*)av = *(const float4*)&Ain[r0 + i][k];
            #pragma unroll
            for (int q = 0; q < 4; q++)
                #pragma unroll
                for (int j = 0; j < 4; j++)
                    acc[i][j] = fmaf(av[q], wk[q][j], acc[i][j]);
        }
    }
    // epilogue: lrelu + dot with attw[128:], reduce over the 32 col-lanes
    float bb[4], ww[4];
    *(float4*)bb = *(const float4*)&b2[c0];
    *(float4*)ww = *(const float4*)&attw[128 + c0];
    float attb = attb1[0];
    float p[8];
    #pragma unroll
    for (int i = 0; i < 8; i++) {
        float s = 0.f;
        #pragma unroll
        for (int j = 0; j < 4; j++) {
            float u = acc[i][j] + bb[j];
            u = u > 0.f ? u : 0.2f * u;
            s = fmaf(ww[j], u, s);
        }
        p[i] = s;
    }
    #pragma unroll
    for (int m = 16; m >= 1; m >>= 1)
        #pragma unroll
        for (int i = 0; i < 8; i++)
            p[i] += __shfl_xor(p[i], m, 64);
    if (tc == 0) {
        #pragma unroll
        for (int i = 0; i < 8; i++) {
            int e = e0 + r0 + i;
            float lg = adst[e >> 4] + p[i] + attb;
            logits[e] = lg > 0.f ? lg : 0.2f * lg;
        }
    }
}

// ---------------- V2 edge logits (pure gather) ----------------
__global__ void k_edge_logits_v2(const float* __restrict__ a, const float* __restrict__ b,
                                 const int* __restrict__ esrc,
                                 const float* __restrict__ biasp, float* __restrict__ logits)
{
    int e = blockIdx.x * 256 + threadIdx.x;
    if (e < EE) {
        float lg = a[e >> 4] + b[esrc[e]] + biasp[0];
        logits[e] = lg > 0.f ? lg : 0.2f * lg;
    }
}

// ---------------- segment softmax (16 contiguous edges/node) + gather + ELU ----------
__global__ void k_aggregate(const float* __restrict__ logits, const int* __restrict__ esrc,
                            const float* __restrict__ V, float* __restrict__ ctx)
{
    int g = threadIdx.x >> 7;
    int c = threadIdx.x & 127;
    int n = blockIdx.x * 2 + g;
    const float* lg = logits + (size_t)n * 16;
    float li[16];
    float m = -1e30f;
    #pragma unroll
    for (int i = 0; i < 16; i++) { li[i] = lg[i]; m = fmaxf(m, li[i]); }
    float den = 0.f;
    #pragma unroll
    for (int i = 0; i < 16; i++) { li[i] = expf(li[i] - m); den += li[i]; }
    float inv = 1.f / den;
    const int* se = esrc + (size_t)n * 16;
    float s = 0.f;
    #pragma unroll
    for (int i = 0; i < 16; i++) {
        int src = se[i];
        s = fmaf(li[i] * inv, V[(size_t)src * 128 + c], s);
    }
    ctx[(size_t)n * 128 + c] = s > 0.f ? s : (expf(s) - 1.f);   // ELU alpha=1
}

// ---------------- GRU gate combine ----------------
// G: [N,384] with cols 0:128 = i_r+h_r, 128:256 = i_z+h_z, 256:384 = i_n ; HN: h_n
__global__ void k_gru_gates(const float* __restrict__ G, const float* __restrict__ HNb,
                            const float* __restrict__ hprev, float* __restrict__ hout)
{
    int idx = blockIdx.x * 256 + threadIdx.x;
    int n = idx >> 7, c = idx & 127;
    float rr = G[(size_t)n * 384 + c];
    float zz = G[(size_t)n * 384 + 128 + c];
    float in_ = G[(size_t)n * 384 + 256 + c];
    float hn = HNb[idx];
    float r = 1.f / (1.f + expf(-rr));
    float z = 1.f / (1.f + expf(-zz));
    float nn2 = tanhf(fmaf(r, hn, in_));
    hout[idx] = fmaf(z, hprev[idx] - nn2, nn2);   // (1-z)*n + z*h
}

// ---------------- mean of 3 ----------------
__global__ void k_avg(const float* __restrict__ a0, const float* __restrict__ a1,
                      const float* __restrict__ a2, float* __restrict__ out)
{
    int idx = blockIdx.x * 256 + threadIdx.x;
    out[idx] = (a0[idx] + a1[idx] + a2[idx]) * (1.f / 3.f);
}

extern "C" void kernel_launch(void* const* d_in, const int* in_sizes, int n_in,
                              void* d_out, int out_size, void* d_ws, size_t ws_size,
                              hipStream_t stream) {
    const float* atom     = (const float*)d_in[0];
    const int*   esrc     = (const int*)d_in[1];
    const float* bond     = (const float*)d_in[3];
    const float* fc1_w    = (const float*)d_in[4];
    const float* fc1_b    = (const float*)d_in[5];
    const float* fc2_w    = (const float*)d_in[6];
    const float* fc2_b    = (const float*)d_in[7];
    const float* att_w    = (const float*)d_in[8];
    const float* att_b    = (const float*)d_in[9];
    const float* attend_w = (const float*)d_in[10];
    const float* attend_b = (const float*)d_in[11];
    const float* gih1     = (const float*)d_in[12];
    const float* ghh1     = (const float*)d_in[13];
    const float* bih1     = (const float*)d_in[14];
    const float* bhh1     = (const float*)d_in[15];
    const float* fc1v2_w  = (const float*)d_in[16];
    const float* fc1v2_b  = (const float*)d_in[17];
    const float* fc2v2_w  = (const float*)d_in[18];
    const float* fc2v2_b  = (const float*)d_in[19];
    const float* gih2     = (const float*)d_in[20];
    const float* ghh2     = (const float*)d_in[21];
    const float* bih2     = (const float*)d_in[22];
    const float* bhh2     = (const float*)d_in[23];
    const float* lin_w    = (const float*)d_in[24];
    const float* lin_b    = (const float*)d_in[25];

    float* ws = (float*)d_ws;
    size_t off = 0;
    auto alloc = [&](size_t n) { size_t o = off; off += n; return o; };
    const size_t oWFC1   = alloc(128 * 128);
    const size_t oWATT   = alloc(128 * 128);
    const size_t oWFC2   = alloc(144 * 128);
    const size_t oWGIH1  = alloc(128 * 384);
    const size_t oWGHH1  = alloc(128 * 384);
    const size_t oWFC2V2 = alloc(128 * 128);
    const size_t oWGIH2  = alloc(128 * 384);
    const size_t oWGHH2  = alloc(128 * 384);
    const size_t oWLIN   = alloc(128 * 128);
    const size_t oNBRT   = alloc((size_t)NN * 128);
    const size_t oCTX    = alloc((size_t)NN * 128);
    const size_t oG      = alloc((size_t)NN * 384);
    const size_t oHN     = alloc((size_t)NN * 128);
    const size_t oLOG    = alloc(EE);
    const size_t oADST   = alloc(NN);
    const size_t oBSRC   = alloc(NN);
    (void)ws_size;

    float* out0 = (float*)d_out;
    float* as0  = out0 + (size_t)NN * 128;        // all_stack[0]
    float* as1  = as0 + (size_t)NN * 128;
    float* as2  = as1 + (size_t)NN * 128;
    float* g0   = out0 + (size_t)4 * NN * 128;    // G_0 slot (= new_atom)
    float* avg  = out0 + (size_t)5 * NN * 128;    // averaged slot

    auto tr = [&](const float* w, size_t o, int rows, int cols) {
        int total = rows * cols;
        k_transpose<<<(total + 255) / 256, 256, 0, stream>>>(w, ws + o, rows, cols);
    };
    tr(fc1_w,    oWFC1,   128, 128);
    tr(attend_w, oWATT,   128, 128);
    tr(fc2_w,    oWFC2,   128, 144);
    tr(gih1,     oWGIH1,  384, 128);
    tr(ghh1,     oWGHH1,  384, 128);
    tr(fc2v2_w,  oWFC2V2, 128, 128);
    tr(gih2,     oWGIH2,  384, 128);
    tr(ghh2,     oWGHH2,  384, 128);
    tr(lin_w,    oWLIN,   128, 128);

    const int MT = (NN + 63) / 64;   // 313

    auto run_gru = [&](const float* ctx, const float* hprev, size_t wih, size_t whh,
                       const float* bih, const float* bhh, float* hout) {
        // r,z: gi+gh summed (cols 0..255)
        k_gemm<0, true><<<dim3(MT, 4), 256, 0, stream>>>(
            ctx, hprev, ws + wih, ws + whh, bih, bhh, ws + oG, NN, 384, 0, 384, 0);
        // i_n (cols 256..383)
        k_gemm<0, false><<<dim3(MT, 2), 256, 0, stream>>>(
            ctx, nullptr, ws + wih, nullptr, bih, nullptr, ws + oG, NN, 384, 256, 384, 256);
        // h_n -> separate buffer
        k_gemm<0, false><<<dim3(MT, 2), 256, 0, stream>>>(
            hprev, nullptr, ws + whh, nullptr, bhh, nullptr, ws + oHN, NN, 384, 256, 128, 0);
        k_gru_gates<<<(NN * 128) / 256, 256, 0, stream>>>(ws + oG, ws + oHN, hprev, hout);
    };

    // ---------------- GATlayerV1 ----------------
    // new_atom = lrelu(fc1(atom))  -> G_0 slot
    k_gemm<1, false><<<dim3(MT, 2), 256, 0, stream>>>(
        atom, nullptr, ws + oWFC1, nullptr, fc1_b, nullptr, g0, NN, 128, 0, 128, 0);
    // nbr_trans = attend(new_atom)
    k_gemm<0, false><<<dim3(MT, 2), 256, 0, stream>>>(
        g0, nullptr, ws + oWATT, nullptr, attend_b, nullptr, ws + oNBRT, NN, 128, 0, 128, 0);
    // a_dst[n] = dot(new_atom[n], att_w[:128])
    k_node_dots<false><<<NN / 4, 256, 0, stream>>>(g0, att_w, ws + oADST, nullptr);
    // edge logits (the big edge GEMM)
    k_edge_logits_v1<<<EE / 64, 256, 0, stream>>>(
        atom, esrc, bond, ws + oWFC2, fc2_b, att_w, att_b, ws + oADST, ws + oLOG);
    // softmax + weighted gather + ELU -> ctx
    k_aggregate<<<NN / 2, 256, 0, stream>>>(ws + oLOG, esrc, ws + oNBRT, ws + oCTX);
    // GRU -> h1 (all_stack[0])
    run_gru(ws + oCTX, g0, oWGIH1, oWGHH1, bih1, bhh1, as0);

    // ---------------- GATlayerV2 x2 ----------------
    const float* h = as0;
    float* houts[2] = { as1, as2 };
    for (int l = 0; l < 2; l++) {
        // nt = fc2(h)
        k_gemm<0, false><<<dim3(MT, 2), 256, 0, stream>>>(
            h, nullptr, ws + oWFC2V2, nullptr, fc2v2_b, nullptr, ws + oNBRT, NN, 128, 0, 128, 0);
        // a[n], b[n] dots against v2_fc1_w
        k_node_dots<true><<<NN / 4, 256, 0, stream>>>(h, fc1v2_w, ws + oADST, ws + oBSRC);
        k_edge_logits_v2<<<(EE + 255) / 256, 256, 0, stream>>>(
            ws + oADST, ws + oBSRC, esrc, fc1v2_b, ws + oLOG);
        k_aggregate<<<NN / 2, 256, 0, stream>>>(ws + oLOG, esrc, ws + oNBRT, ws + oCTX);
        run_gru(ws + oCTX, h, oWGIH2, oWGHH2, bih2, bhh2, houts[l]);
        h = houts[l];
    }

    // ---------------- final ----------------
    k_avg<<<(NN * 128) / 256, 256, 0, stream>>>(as0, as1, as2, avg);
    k_gemm<2, false><<<dim3(MT, 2), 256, 0, stream>>>(
        avg, nullptr, ws + oWLIN, nullptr, lin_b, nullptr, out0, NN, 128, 0, 128, 0);
}

// Round 2
// 228.978 us; speedup vs baseline: 2.8559x; 2.8559x over previous
//
#include <hip/hip_runtime.h>
#include <math.h>

#define NN 20000
#define EE 320000

using short8 = __attribute__((ext_vector_type(8))) short;
using f32x4  = __attribute__((ext_vector_type(4))) float;
using u16x4  = __attribute__((ext_vector_type(4))) unsigned short;

__device__ __forceinline__ unsigned short f2bf(float x) {
    union { float f; unsigned u; } v; v.f = x;
    unsigned r = (v.u + 0x7fffu + ((v.u >> 16) & 1u)) >> 16;
    return (unsigned short)r;
}
__device__ __forceinline__ float bf2f(unsigned short b) {
    union { unsigned u; float f; } v; v.u = ((unsigned)b) << 16;
    return v.f;
}
__device__ __forceinline__ float sigmoidf_(float x) { return 1.f / (1.f + __expf(-x)); }
__device__ __forceinline__ float tanhf_(float x) {
    float e = __expf(-2.f * x);
    return (1.f - e) / (1.f + e);
}

// ---------------- weight pack into MFMA B-fragment layout ----------------
// B[k][o] = w[o][k];  frag elem (tile no, ktile ko, lane l, j) =
//   w[no*16 + (l&15)][ko*32 + (l>>4)*8 + j]; stored at ((no*4+ko)*64+l)*8+j. K=128 fixed.
struct PackDesc { const float* w; unsigned short* out; int O; int ldw; };
struct PackArgs { PackDesc d[9]; };

__global__ void k_pack(PackArgs args) {
    PackDesc d = args.d[blockIdx.y];
    int total = (d.O / 16) * 4 * 64;
    int idx = blockIdx.x * 256 + threadIdx.x;
    if (idx >= total) return;
    int l = idx & 63, rest = idx >> 6;
    int ko = rest & 3, no = rest >> 2;
    int row = no * 16 + (l & 15);
    int col0 = ko * 32 + ((l >> 4) * 8);
    const float* src = d.w + (size_t)row * d.ldw + col0;
    unsigned short o[8];
    #pragma unroll
    for (int j = 0; j < 8; j++) o[j] = f2bf(src[j]);
    #pragma unroll
    for (int j = 0; j < 8; j++) d.out[(size_t)idx * 8 + j] = o[j];
}

// ---------------- f32 -> bf16 convert ----------------
__global__ void k_cvt(const float* __restrict__ in, unsigned short* __restrict__ out, int n4) {
    int i = blockIdx.x * 256 + threadIdx.x;
    if (i < n4) {
        float4 v = ((const float4*)in)[i];
        u16x4 o;
        o[0] = f2bf(v.x); o[1] = f2bf(v.y); o[2] = f2bf(v.z); o[3] = f2bf(v.w);
        ((u16x4*)out)[i] = o;
    }
}

// ---------------- generic node GEMM (O=128): out_bf = A@W^T + b ----------------
__global__ __launch_bounds__(256) void k_node_gemm(
    const unsigned short* __restrict__ A, const unsigned short* __restrict__ Bp,
    const float* __restrict__ bias, unsigned short* __restrict__ outBf)
{
    __shared__ unsigned short Ys[16 * 128];
    const int tid = threadIdx.x, l = tid & 63, w = tid >> 6;
    const int lr = l & 15, lg = l >> 4;
    const int m0 = blockIdx.x * 16;
    f32x4 acc[2] = {};
    const unsigned short* Arow = A + (size_t)(m0 + lr) * 128 + lg * 8;
    #pragma unroll
    for (int ko = 0; ko < 4; ko++) {
        short8 af = *(const short8*)(Arow + ko * 32);
        #pragma unroll
        for (int i = 0; i < 2; i++) {
            int t = w * 2 + i;
            short8 bf = *(const short8*)(Bp + ((size_t)(t * 4 + ko) * 64 + l) * 8);
            acc[i] = __builtin_amdgcn_mfma_f32_16x16x32_bf16(af, bf, acc[i], 0, 0, 0);
        }
    }
    #pragma unroll
    for (int i = 0; i < 2; i++) {
        int col = (w * 2 + i) * 16 + lr;
        float bb = bias[col];
        #pragma unroll
        for (int r = 0; r < 4; r++)
            Ys[(lg * 4 + r) * 128 + col] = f2bf(acc[i][r] + bb);
    }
    __syncthreads();
    *(short8*)(outBf + (size_t)m0 * 128 + tid * 8) = *(const short8*)(Ys + tid * 8);
}

// ---------------- V1 front: new_atom = lrelu(fc1(atom)); nbr_trans = attend(new_atom);
//                  adst = dot(new_atom, att_w[:128]) ----------------
__global__ __launch_bounds__(256) void k_v1_front(
    const unsigned short* __restrict__ atomBf,
    const unsigned short* __restrict__ Bfc1, const unsigned short* __restrict__ Batt,
    const float* __restrict__ fc1_b, const float* __restrict__ attend_b,
    const float* __restrict__ attw,
    float* __restrict__ g0, unsigned short* __restrict__ naBf,
    unsigned short* __restrict__ nbrt, float* __restrict__ adst)
{
    __shared__ float Xs[16][132];
    __shared__ unsigned short Ys[16 * 128];
    const int tid = threadIdx.x, l = tid & 63, w = tid >> 6;
    const int lr = l & 15, lg = l >> 4;
    const int m0 = blockIdx.x * 16;

    // GEMM1: fc1 + lrelu
    f32x4 acc[2] = {};
    const unsigned short* Arow = atomBf + (size_t)(m0 + lr) * 128 + lg * 8;
    #pragma unroll
    for (int ko = 0; ko < 4; ko++) {
        short8 af = *(const short8*)(Arow + ko * 32);
        #pragma unroll
        for (int i = 0; i < 2; i++) {
            int t = w * 2 + i;
            short8 bf = *(const short8*)(Bfc1 + ((size_t)(t * 4 + ko) * 64 + l) * 8);
            acc[i] = __builtin_amdgcn_mfma_f32_16x16x32_bf16(af, bf, acc[i], 0, 0, 0);
        }
    }
    #pragma unroll
    for (int i = 0; i < 2; i++) {
        int col = (w * 2 + i) * 16 + lr;
        float bb = fc1_b[col];
        #pragma unroll
        for (int r = 0; r < 4; r++) {
            int row = lg * 4 + r;
            float v = acc[i][r] + bb;
            v = v > 0.f ? v : 0.2f * v;
            Xs[row][col] = v;
            g0[(size_t)(m0 + row) * 128 + col] = v;
        }
    }
    __syncthreads();

    // bf16 copy of new_atom + adst dot
    {
        int row = tid >> 4, q = tid & 15;
        short8 tmp;
        float p = 0.f;
        #pragma unroll
        for (int j = 0; j < 8; j++) {
            float x = Xs[row][q * 8 + j];
            tmp[j] = (short)f2bf(x);
            p = fmaf(x, attw[q * 8 + j], p);
        }
        *(short8*)(naBf + (size_t)(m0 + row) * 128 + q * 8) = tmp;
        #pragma unroll
        for (int m = 1; m <= 8; m <<= 1) p += __shfl_xor(p, m, 16);
        if (q == 0) adst[m0 + row] = p;
    }

    // GEMM2: attend (A from Xs)
    f32x4 acc2[2] = {};
    #pragma unroll
    for (int ko = 0; ko < 4; ko++) {
        short8 af;
        const float* xp = &Xs[lr][ko * 32 + lg * 8];
        #pragma unroll
        for (int j = 0; j < 8; j++) af[j] = (short)f2bf(xp[j]);
        #pragma unroll
        for (int i = 0; i < 2; i++) {
            int t = w * 2 + i;
            short8 bf = *(const short8*)(Batt + ((size_t)(t * 4 + ko) * 64 + l) * 8);
            acc2[i] = __builtin_amdgcn_mfma_f32_16x16x32_bf16(af, bf, acc2[i], 0, 0, 0);
        }
    }
    #pragma unroll
    for (int i = 0; i < 2; i++) {
        int col = (w * 2 + i) * 16 + lr;
        float bb = attend_b[col];
        #pragma unroll
        for (int r = 0; r < 4; r++)
            Ys[(lg * 4 + r) * 128 + col] = f2bf(acc2[i][r] + bb);
    }
    __syncthreads();
    *(short8*)(nbrt + (size_t)m0 * 128 + tid * 8) = *(const short8*)(Ys + tid * 8);
}

// ---------------- V1 edge logits via U-decomposition ----------------
// logit_e = lrelu( adst[dst] + attb + sum_c attw2_c * lrelu( U[src][c] + (W2b bond_e)_c ) )
__global__ __launch_bounds__(256) void k_edge_v1(
    const unsigned short* __restrict__ U, const int* __restrict__ esrc,
    const float* __restrict__ bond, const float* __restrict__ fc2w,
    const float* __restrict__ attw, const float* __restrict__ attb1,
    const float* __restrict__ adst, float* __restrict__ logits)
{
    const int tid = threadIdx.x, l = tid & 63, w = tid >> 6;
    const int c0 = l * 2;
    float w2b0[16], w2b1[16];
    #pragma unroll
    for (int j = 0; j < 4; j++) {
        float4 a = *(const float4*)(fc2w + (size_t)c0 * 144 + 128 + j * 4);
        float4 b = *(const float4*)(fc2w + (size_t)(c0 + 1) * 144 + 128 + j * 4);
        w2b0[j * 4 + 0] = a.x; w2b0[j * 4 + 1] = a.y; w2b0[j * 4 + 2] = a.z; w2b0[j * 4 + 3] = a.w;
        w2b1[j * 4 + 0] = b.x; w2b1[j * 4 + 1] = b.y; w2b1[j * 4 + 2] = b.z; w2b1[j * 4 + 3] = b.w;
    }
    const float aw0 = attw[128 + c0], aw1 = attw[129 + c0];
    const float attb = attb1[0];
    const int e0 = (blockIdx.x * 4 + w) * 16;
    for (int i = 0; i < 16; i++) {
        int e = e0 + i;
        int src = esrc[e];
        const float* bp = bond + (size_t)e * 16;
        float bj[16];
        #pragma unroll
        for (int j = 0; j < 4; j++) {
            float4 b4 = *(const float4*)(bp + j * 4);
            bj[j * 4 + 0] = b4.x; bj[j * 4 + 1] = b4.y; bj[j * 4 + 2] = b4.z; bj[j * 4 + 3] = b4.w;
        }
        unsigned uu = *(const unsigned*)(U + (size_t)src * 128 + c0);
        float y0 = bf2f((unsigned short)(uu & 0xffffu));
        float y1 = bf2f((unsigned short)(uu >> 16));
        #pragma unroll
        for (int j = 0; j < 16; j++) {
            y0 = fmaf(bj[j], w2b0[j], y0);
            y1 = fmaf(bj[j], w2b1[j], y1);
        }
        y0 = y0 > 0.f ? y0 : 0.2f * y0;
        y1 = y1 > 0.f ? y1 : 0.2f * y1;
        float s = aw0 * y0 + aw1 * y1;
        #pragma unroll
        for (int m = 32; m >= 1; m >>= 1) s += __shfl_xor(s, m, 64);
        if (l == 0) {
            float lg = adst[e >> 4] + attb + s;
            logits[e] = lg > 0.f ? lg : 0.2f * lg;
        }
    }
}

// ---------------- V2 edge logits ----------------
__global__ void k_edge_v2(const float* __restrict__ a, const float* __restrict__ b,
                          const int* __restrict__ esrc,
                          const float* __restrict__ biasp, float* __restrict__ logits)
{
    int e = blockIdx.x * 256 + threadIdx.x;
    if (e < EE) {
        float lg = a[e >> 4] + b[esrc[e]] + biasp[0];
        logits[e] = lg > 0.f ? lg : 0.2f * lg;
    }
}

// ---------------- segment softmax + weighted gather + ELU -> ctx bf16 ----------------
__global__ __launch_bounds__(256) void k_aggregate(
    const float* __restrict__ logits, const int* __restrict__ esrc,
    const unsigned short* __restrict__ V, unsigned short* __restrict__ ctxBf)
{
    const int tid = threadIdx.x;
    const int node = blockIdx.x * 8 + (tid >> 5);
    const int q = tid & 31;
    const float* lg = logits + (size_t)node * 16;
    float li[16], m = -1e30f;
    #pragma unroll
    for (int i = 0; i < 16; i++) { li[i] = lg[i]; m = fmaxf(m, li[i]); }
    float den = 0.f;
    #pragma unroll
    for (int i = 0; i < 16; i++) { li[i] = __expf(li[i] - m); den += li[i]; }
    float inv = 1.f / den;
    const int* se = esrc + (size_t)node * 16;
    float s[4] = {};
    #pragma unroll
    for (int i = 0; i < 16; i++) {
        int src = se[i];
        u16x4 vv = *(const u16x4*)(V + (size_t)src * 128 + q * 4);
        float wgt = li[i] * inv;
        #pragma unroll
        for (int j = 0; j < 4; j++) s[j] = fmaf(wgt, bf2f(vv[j]), s[j]);
    }
    u16x4 o;
    #pragma unroll
    for (int j = 0; j < 4; j++) {
        float v = s[j];
        v = v > 0.f ? v : (__expf(v) - 1.f);
        o[j] = f2bf(v);
    }
    *(u16x4*)(ctxBf + (size_t)node * 128 + q * 4) = o;
}

// ---------------- fused GRU: gi = ctx@wih^T, gh = h@whh^T, gates, h writeback ------
__global__ __launch_bounds__(256) void k_gru(
    const unsigned short* __restrict__ ctxBf, const unsigned short* __restrict__ hBf,
    const unsigned short* __restrict__ Bih, const unsigned short* __restrict__ Bhh,
    const float* __restrict__ bih, const float* __restrict__ bhh,
    const float* __restrict__ hprevF, float* __restrict__ houtF,
    unsigned short* __restrict__ houtBf)
{
    __shared__ float Gs[16][772];
    const int tid = threadIdx.x, l = tid & 63, w = tid >> 6;
    const int lr = l & 15, lg = l >> 4;
    const int m0 = blockIdx.x * 16;
    f32x4 acc[12] = {};
    const unsigned short* Ac = ctxBf + (size_t)(m0 + lr) * 128 + lg * 8;
    const unsigned short* Ah = hBf   + (size_t)(m0 + lr) * 128 + lg * 8;
    #pragma unroll
    for (int ko = 0; ko < 4; ko++) {
        short8 afc = *(const short8*)(Ac + ko * 32);
        short8 afh = *(const short8*)(Ah + ko * 32);
        #pragma unroll
        for (int i = 0; i < 6; i++) {
            int t = w + 4 * i;
            short8 bf = *(const short8*)(Bih + ((size_t)(t * 4 + ko) * 64 + l) * 8);
            acc[i] = __builtin_amdgcn_mfma_f32_16x16x32_bf16(afc, bf, acc[i], 0, 0, 0);
        }
        #pragma unroll
        for (int i = 0; i < 6; i++) {
            int t = w + 4 * i;
            short8 bf = *(const short8*)(Bhh + ((size_t)(t * 4 + ko) * 64 + l) * 8);
            acc[6 + i] = __builtin_amdgcn_mfma_f32_16x16x32_bf16(afh, bf, acc[6 + i], 0, 0, 0);
        }
    }
    #pragma unroll
    for (int i = 0; i < 6; i++) {
        int t = w + 4 * i;
        #pragma unroll
        for (int r = 0; r < 4; r++) {
            Gs[lg * 4 + r][t * 16 + lr]       = acc[i][r];
            Gs[lg * 4 + r][384 + t * 16 + lr] = acc[6 + i][r];
        }
    }
    __syncthreads();
    {
        const int row = tid & 15, q = tid >> 4;
        const int c0 = q * 8;
        const int grow = m0 + row;
        const float* gr = Gs[row];
        float gir[8], giz[8], gin[8], ghr[8], ghz[8], ghn[8], hp[8];
        float br1[8], bz1[8], bn1[8], br2[8], bz2[8], bn2[8];
        auto ld8s = [](float* dst, const float* p) {
            *(float4*)dst = *(const float4*)p; *(float4*)(dst + 4) = *(const float4*)(p + 4);
        };
        ld8s(gir, gr + c0);        ld8s(giz, gr + 128 + c0); ld8s(gin, gr + 256 + c0);
        ld8s(ghr, gr + 384 + c0);  ld8s(ghz, gr + 512 + c0); ld8s(ghn, gr + 640 + c0);
        ld8s(br1, bih + c0); ld8s(bz1, bih + 128 + c0); ld8s(bn1, bih + 256 + c0);
        ld8s(br2, bhh + c0); ld8s(bz2, bhh + 128 + c0); ld8s(bn2, bhh + 256 + c0);
        ld8s(hp, hprevF + (size_t)grow * 128 + c0);
        float ho[8];
        short8 hob;
        #pragma unroll
        for (int j = 0; j < 8; j++) {
            float r = sigmoidf_(gir[j] + ghr[j] + br1[j] + br2[j]);
            float z = sigmoidf_(giz[j] + ghz[j] + bz1[j] + bz2[j]);
            float n = tanhf_(fmaf(r, ghn[j] + bn2[j], gin[j] + bn1[j]));
            ho[j] = fmaf(z, hp[j] - n, n);
            hob[j] = (short)f2bf(ho[j]);
        }
        *(float4*)(houtF + (size_t)grow * 128 + c0)     = *(float4*)ho;
        *(float4*)(houtF + (size_t)grow * 128 + c0 + 4) = *(float4*)(ho + 4);
        *(short8*)(houtBf + (size_t)grow * 128 + c0) = hob;
    }
}

// ---------------- V2 front: nt = fc2(h); a,b node dots vs v2_fc1_w ----------------
__global__ __launch_bounds__(256) void k_v2_front(
    const unsigned short* __restrict__ hBf, const unsigned short* __restrict__ Bfc2,
    const float* __restrict__ fc2b, const float* __restrict__ w2att,
    unsigned short* __restrict__ nt, float* __restrict__ aD, float* __restrict__ bS)
{
    __shared__ unsigned short Ys[16 * 128];
    const int tid = threadIdx.x, l = tid & 63, w = tid >> 6;
    const int lr = l & 15, lg = l >> 4;
    const int m0 = blockIdx.x * 16;
    // dots
    {
        int row = tid >> 4, q = tid & 15;
        short8 hv = *(const short8*)(hBf + (size_t)(m0 + row) * 128 + q * 8);
        float pa = 0.f, pb = 0.f;
        #pragma unroll
        for (int j = 0; j < 8; j++) {
            float x = bf2f((unsigned short)hv[j]);
            pa = fmaf(x, w2att[q * 8 + j], pa);
            pb = fmaf(x, w2att[128 + q * 8 + j], pb);
        }
        #pragma unroll
        for (int m = 1; m <= 8; m <<= 1) {
            pa += __shfl_xor(pa, m, 16);
            pb += __shfl_xor(pb, m, 16);
        }
        if (q == 0) { aD[m0 + row] = pa; bS[m0 + row] = pb; }
    }
    // GEMM
    f32x4 acc[2] = {};
    const unsigned short* Arow = hBf + (size_t)(m0 + lr) * 128 + lg * 8;
    #pragma unroll
    for (int ko = 0; ko < 4; ko++) {
        short8 af = *(const short8*)(Arow + ko * 32);
        #pragma unroll
        for (int i = 0; i < 2; i++) {
            int t = w * 2 + i;
            short8 bf = *(const short8*)(Bfc2 + ((size_t)(t * 4 + ko) * 64 + l) * 8);
            acc[i] = __builtin_amdgcn_mfma_f32_16x16x32_bf16(af, bf, acc[i], 0, 0, 0);
        }
    }
    #pragma unroll
    for (int i = 0; i < 2; i++) {
        int col = (w * 2 + i) * 16 + lr;
        float bb = fc2b[col];
        #pragma unroll
        for (int r = 0; r < 4; r++)
            Ys[(lg * 4 + r) * 128 + col] = f2bf(acc[i][r] + bb);
    }
    __syncthreads();
    *(short8*)(nt + (size_t)m0 * 128 + tid * 8) = *(const short8*)(Ys + tid * 8);
}

// ---------------- final: avg + lin + gelu ----------------
__global__ __launch_bounds__(256) void k_final(
    const float* __restrict__ a0, const float* __restrict__ a1, const float* __restrict__ a2,
    const unsigned short* __restrict__ Blin, const float* __restrict__ linb,
    float* __restrict__ avgOut, float* __restrict__ out)
{
    __shared__ unsigned short Ys[16 * 136];
    const int tid = threadIdx.x, l = tid & 63, w = tid >> 6;
    const int lr = l & 15, lg = l >> 4;
    const int m0 = blockIdx.x * 16;
    {
        int row = tid >> 4, q = tid & 15;
        size_t base = (size_t)(m0 + row) * 128 + q * 8;
        float v[8];
        #pragma unroll
        for (int h = 0; h < 2; h++) {
            float4 x0 = *(const float4*)(a0 + base + h * 4);
            float4 x1 = *(const float4*)(a1 + base + h * 4);
            float4 x2 = *(const float4*)(a2 + base + h * 4);
            v[h * 4 + 0] = (x0.x + x1.x + x2.x) * (1.f / 3.f);
            v[h * 4 + 1] = (x0.y + x1.y + x2.y) * (1.f / 3.f);
            v[h * 4 + 2] = (x0.z + x1.z + x2.z) * (1.f / 3.f);
            v[h * 4 + 3] = (x0.w + x1.w + x2.w) * (1.f / 3.f);
        }
        *(float4*)(avgOut + base) = *(float4*)v;
        *(float4*)(avgOut + base + 4) = *(float4*)(v + 4);
        #pragma unroll
        for (int j = 0; j < 8; j++) Ys[row * 136 + q * 8 + j] = f2bf(v[j]);
    }
    __syncthreads();
    f32x4 acc[2] = {};
    #pragma unroll
    for (int ko = 0; ko < 4; ko++) {
        short8 af = *(const short8*)(Ys + lr * 136 + ko * 32 + lg * 8);
        #pragma unroll
        for (int i = 0; i < 2; i++) {
            int t = w * 2 + i;
            short8 bf = *(const short8*)(Blin + ((size_t)(t * 4 + ko) * 64 + l) * 8);
            acc[i] = __builtin_amdgcn_mfma_f32_16x16x32_bf16(af, bf, acc[i], 0, 0, 0);
        }
    }
    #pragma unroll
    for (int i = 0; i < 2; i++) {
        int col = (w * 2 + i) * 16 + lr;
        float bb = linb[col];
        #pragma unroll
        for (int r = 0; r < 4; r++) {
            float vv = acc[i][r] + bb;
            vv = 0.5f * vv * (1.f + erff(vv * 0.70710678118654752f));
            out[(size_t)(m0 + lg * 4 + r) * 128 + col] = vv;
        }
    }
}

extern "C" void kernel_launch(void* const* d_in, const int* in_sizes, int n_in,
                              void* d_out, int out_size, void* d_ws, size_t ws_size,
                              hipStream_t stream) {
    const float* atom     = (const float*)d_in[0];
    const int*   esrc     = (const int*)d_in[1];
    const float* bond     = (const float*)d_in[3];
    const float* fc1_w    = (const float*)d_in[4];
    const float* fc1_b    = (const float*)d_in[5];
    const float* fc2_w    = (const float*)d_in[6];
    const float* fc2_b    = (const float*)d_in[7];
    const float* att_w    = (const float*)d_in[8];
    const float* att_b    = (const float*)d_in[9];
    const float* attend_w = (const float*)d_in[10];
    const float* attend_b = (const float*)d_in[11];
    const float* gih1     = (const float*)d_in[12];
    const float* ghh1     = (const float*)d_in[13];
    const float* bih1     = (const float*)d_in[14];
    const float* bhh1     = (const float*)d_in[15];
    const float* fc1v2_w  = (const float*)d_in[16];
    const float* fc1v2_b  = (const float*)d_in[17];
    const float* fc2v2_w  = (const float*)d_in[18];
    const float* fc2v2_b  = (const float*)d_in[19];
    const float* gih2     = (const float*)d_in[20];
    const float* ghh2     = (const float*)d_in[21];
    const float* bih2     = (const float*)d_in[22];
    const float* bhh2     = (const float*)d_in[23];
    const float* lin_w    = (const float*)d_in[24];
    const float* lin_b    = (const float*)d_in[25];

    char* wsb = (char*)d_ws;
    size_t off = 0;
    auto allocB = [&](size_t bytes) {
        size_t o = off; off = (off + bytes + 255) & ~(size_t)255; return o;
    };
    unsigned short* Bfc1   = (unsigned short*)(wsb + allocB(128 * 128 * 2));
    unsigned short* Batt   = (unsigned short*)(wsb + allocB(128 * 128 * 2));
    unsigned short* BW2a   = (unsigned short*)(wsb + allocB(128 * 128 * 2));
    unsigned short* Bgih1  = (unsigned short*)(wsb + allocB(384 * 128 * 2));
    unsigned short* Bghh1  = (unsigned short*)(wsb + allocB(384 * 128 * 2));
    unsigned short* Bfc2v2 = (unsigned short*)(wsb + allocB(128 * 128 * 2));
    unsigned short* Bgih2  = (unsigned short*)(wsb + allocB(384 * 128 * 2));
    unsigned short* Bghh2  = (unsigned short*)(wsb + allocB(384 * 128 * 2));
    unsigned short* Blin   = (unsigned short*)(wsb + allocB(128 * 128 * 2));
    unsigned short* atomBf = (unsigned short*)(wsb + allocB((size_t)NN * 128 * 2));
    unsigned short* naBf   = (unsigned short*)(wsb + allocB((size_t)NN * 128 * 2));
    unsigned short* Ubf    = (unsigned short*)(wsb + allocB((size_t)NN * 128 * 2));
    unsigned short* nbrt   = (unsigned short*)(wsb + allocB((size_t)NN * 128 * 2));
    unsigned short* ctxBf  = (unsigned short*)(wsb + allocB((size_t)NN * 128 * 2));
    unsigned short* h1Bf   = (unsigned short*)(wsb + allocB((size_t)NN * 128 * 2));
    unsigned short* h2Bf   = (unsigned short*)(wsb + allocB((size_t)NN * 128 * 2));
    float* logits = (float*)(wsb + allocB((size_t)EE * 4));
    float* adst   = (float*)(wsb + allocB((size_t)NN * 4));
    float* bsrc   = (float*)(wsb + allocB((size_t)NN * 4));
    (void)ws_size;

    float* out0 = (float*)d_out;
    float* as0  = out0 + (size_t)NN * 128;
    float* as1  = as0 + (size_t)NN * 128;
    float* as2  = as1 + (size_t)NN * 128;
    float* g0   = out0 + (size_t)4 * NN * 128;
    float* avg  = out0 + (size_t)5 * NN * 128;

    // pack all weights
    PackArgs pa;
    pa.d[0] = { fc1_w,    Bfc1,   128, 128 };
    pa.d[1] = { attend_w, Batt,   128, 128 };
    pa.d[2] = { fc2_w,    BW2a,   128, 144 };   // first 128 K-cols of fc2_w
    pa.d[3] = { gih1,     Bgih1,  384, 128 };
    pa.d[4] = { ghh1,     Bghh1,  384, 128 };
    pa.d[5] = { fc2v2_w,  Bfc2v2, 128, 128 };
    pa.d[6] = { gih2,     Bgih2,  384, 128 };
    pa.d[7] = { ghh2,     Bghh2,  384, 128 };
    pa.d[8] = { lin_w,    Blin,   128, 128 };
    k_pack<<<dim3(24, 9), 256, 0, stream>>>(pa);

    // atom -> bf16
    k_cvt<<<(NN * 128 / 4 + 255) / 256, 256, 0, stream>>>(atom, atomBf, NN * 128 / 4);

    const int GB = NN / 16;  // 1250

    // ---- V1 ----
    k_v1_front<<<GB, 256, 0, stream>>>(atomBf, Bfc1, Batt, fc1_b, attend_b, att_w,
                                       g0, naBf, nbrt, adst);
    k_node_gemm<<<GB, 256, 0, stream>>>(atomBf, BW2a, fc2_b, Ubf);
    k_edge_v1<<<EE / 64, 256, 0, stream>>>(Ubf, esrc, bond, fc2_w, att_w, att_b,
                                           adst, logits);
    k_aggregate<<<NN / 8, 256, 0, stream>>>(logits, esrc, nbrt, ctxBf);
    k_gru<<<GB, 256, 0, stream>>>(ctxBf, naBf, Bgih1, Bghh1, bih1, bhh1, g0, as0, h1Bf);

    // ---- V2 x2 ----
    const unsigned short* hBfIn = h1Bf;
    const float* hFIn = as0;
    unsigned short* hBfOut[2] = { h2Bf, h1Bf };
    float* hFOut[2] = { as1, as2 };
    for (int lyr = 0; lyr < 2; lyr++) {
        k_v2_front<<<GB, 256, 0, stream>>>(hBfIn, Bfc2v2, fc2v2_b, fc1v2_w,
                                           nbrt, adst, bsrc);
        k_edge_v2<<<EE / 256, 256, 0, stream>>>(adst, bsrc, esrc, fc1v2_b, logits);
        k_aggregate<<<NN / 8, 256, 0, stream>>>(logits, esrc, nbrt, ctxBf);
        k_gru<<<GB, 256, 0, stream>>>(ctxBf, hBfIn, Bgih2, Bghh2, bih2, bhh2,
                                      hFIn, hFOut[lyr], hBfOut[lyr]);
        hBfIn = hBfOut[lyr];
        hFIn = hFOut[lyr];
    }

    // ---- final ----
    k_final<<<GB, 256, 0, stream>>>(as0, as1, as2, Blin, lin_b, avg, out0);
}

// Round 3
// 181.484 us; speedup vs baseline: 3.6032x; 1.2617x over previous
//
#include <hip/hip_runtime.h>
#include <math.h>

#define NN 20000
#define EE 320000

using short8 = __attribute__((ext_vector_type(8))) short;
using f32x4  = __attribute__((ext_vector_type(4))) float;

__device__ __forceinline__ unsigned short f2bf(float x) {
    union { float f; unsigned u; } v; v.f = x;
    unsigned r = (v.u + 0x7fffu + ((v.u >> 16) & 1u)) >> 16;
    return (unsigned short)r;
}
__device__ __forceinline__ float bf2f(unsigned short b) {
    union { unsigned u; float f; } v; v.u = ((unsigned)b) << 16;
    return v.f;
}
__device__ __forceinline__ float sigmoidf_(float x) { return 1.f / (1.f + __expf(-x)); }
__device__ __forceinline__ float tanhf_(float x) {
    float e = __expf(-2.f * x);
    return (1.f - e) / (1.f + e);
}
__device__ __forceinline__ float lrelu_(float x) { return x > 0.f ? x : 0.2f * x; }

// ---------------- weight pack into MFMA B-fragment layout (K=128) ----------------
// value(tile no, ktile ko, lane l, j) = w[no*16 + (l&15)][ko*32 + (l>>4)*8 + j]
struct PackDesc { const float* w; unsigned short* out; int O; int ldw; };
struct PackArgs { PackDesc d[9]; };

__global__ void k_pack(PackArgs args) {
    PackDesc d = args.d[blockIdx.y];
    int total = (d.O / 16) * 4 * 64;
    int idx = blockIdx.x * 256 + threadIdx.x;
    if (idx >= total) return;
    int l = idx & 63, rest = idx >> 6;
    int ko = rest & 3, no = rest >> 2;
    int row = no * 16 + (l & 15);
    int col0 = ko * 32 + ((l >> 4) * 8);
    const float* src = d.w + (size_t)row * d.ldw + col0;
    unsigned short o[8];
    #pragma unroll
    for (int j = 0; j < 8; j++) o[j] = f2bf(src[j]);
    #pragma unroll
    for (int j = 0; j < 8; j++) d.out[(size_t)idx * 8 + j] = o[j];
}

// ---------------- pack W2b (bond part of fc2_w) into B-frags, K=32 zero-padded ----
// tile t covers channels ch = col*8 + t (col = l&15). k = (l>>4)*8+j, valid k<16.
__global__ void k_pack_w2b(const float* __restrict__ fc2w, unsigned short* __restrict__ out) {
    int idx = blockIdx.x * 256 + threadIdx.x;   // 0..511
    if (idx >= 512) return;
    int t = idx >> 6, l = idx & 63;
    int lr = l & 15, lg = l >> 4;
    int ch = lr * 8 + t;
    short8 o;
    #pragma unroll
    for (int j = 0; j < 8; j++) {
        int k = lg * 8 + j;
        o[j] = (k < 16) ? (short)f2bf(fc2w[(size_t)ch * 144 + 128 + k]) : (short)0;
    }
    *(short8*)(out + (size_t)idx * 8) = o;
}

// ---------------- V1 front: new_atom=lrelu(fc1(atom)) -> g0,Xs,naBf ; U=atom@W2a+b2 ;
//                  nbr_trans=attend(new_atom) ; adst=dot(new_atom, att_w[:128]) -----
__global__ __launch_bounds__(256) void k_v1_front(
    const float* __restrict__ atom,
    const unsigned short* __restrict__ Bfc1, const unsigned short* __restrict__ BW2a,
    const unsigned short* __restrict__ Batt,
    const float* __restrict__ fc1_b, const float* __restrict__ fc2_b,
    const float* __restrict__ attend_b, const float* __restrict__ attw,
    float* __restrict__ g0, unsigned short* __restrict__ naBf,
    unsigned short* __restrict__ Ubf, unsigned short* __restrict__ nbrt,
    float* __restrict__ adst)
{
    __shared__ float Xs[16][132];
    __shared__ unsigned short Ys[16 * 128];
    __shared__ unsigned short Ys2[16 * 128];
    const int tid = threadIdx.x, l = tid & 63, w = tid >> 6;
    const int lr = l & 15, lg = l >> 4;
    const int m0 = blockIdx.x * 16;

    // GEMM1 (fc1) + GEMM-U (W2a), shared A-frags from f32 atom
    f32x4 acc1[2] = {}, accU[2] = {};
    #pragma unroll
    for (int ko = 0; ko < 4; ko++) {
        const float* ap = atom + (size_t)(m0 + lr) * 128 + ko * 32 + lg * 8;
        float4 a0 = *(const float4*)ap, a1 = *(const float4*)(ap + 4);
        short8 af;
        af[0] = (short)f2bf(a0.x); af[1] = (short)f2bf(a0.y);
        af[2] = (short)f2bf(a0.z); af[3] = (short)f2bf(a0.w);
        af[4] = (short)f2bf(a1.x); af[5] = (short)f2bf(a1.y);
        af[6] = (short)f2bf(a1.z); af[7] = (short)f2bf(a1.w);
        #pragma unroll
        for (int i = 0; i < 2; i++) {
            int t = w * 2 + i;
            short8 b1 = *(const short8*)(Bfc1 + ((size_t)(t * 4 + ko) * 64 + l) * 8);
            acc1[i] = __builtin_amdgcn_mfma_f32_16x16x32_bf16(af, b1, acc1[i], 0, 0, 0);
            short8 bu = *(const short8*)(BW2a + ((size_t)(t * 4 + ko) * 64 + l) * 8);
            accU[i] = __builtin_amdgcn_mfma_f32_16x16x32_bf16(af, bu, accU[i], 0, 0, 0);
        }
    }
    #pragma unroll
    for (int i = 0; i < 2; i++) {
        int col = (w * 2 + i) * 16 + lr;
        float b1v = fc1_b[col], bUv = fc2_b[col];
        #pragma unroll
        for (int r = 0; r < 4; r++) {
            int row = lg * 4 + r;
            float v = lrelu_(acc1[i][r] + b1v);
            Xs[row][col] = v;
            g0[(size_t)(m0 + row) * 128 + col] = v;
            Ys2[row * 128 + col] = f2bf(accU[i][r] + bUv);
        }
    }
    __syncthreads();
    // store U ; bf16 new_atom + adst dot
    *(short8*)(Ubf + (size_t)m0 * 128 + tid * 8) = *(const short8*)(Ys2 + tid * 8);
    {
        int row = tid >> 4, q = tid & 15;
        short8 tmp;
        float p = 0.f;
        #pragma unroll
        for (int j = 0; j < 8; j++) {
            float x = Xs[row][q * 8 + j];
            tmp[j] = (short)f2bf(x);
            p = fmaf(x, attw[q * 8 + j], p);
        }
        *(short8*)(naBf + (size_t)(m0 + row) * 128 + q * 8) = tmp;
        #pragma unroll
        for (int m = 1; m <= 8; m <<= 1) p += __shfl_xor(p, m, 16);
        if (q == 0) adst[m0 + row] = p;
    }
    // GEMM2: attend (A from Xs)
    f32x4 acc2[2] = {};
    #pragma unroll
    for (int ko = 0; ko < 4; ko++) {
        short8 af;
        const float* xp = &Xs[lr][ko * 32 + lg * 8];
        #pragma unroll
        for (int j = 0; j < 8; j++) af[j] = (short)f2bf(xp[j]);
        #pragma unroll
        for (int i = 0; i < 2; i++) {
            int t = w * 2 + i;
            short8 bf = *(const short8*)(Batt + ((size_t)(t * 4 + ko) * 64 + l) * 8);
            acc2[i] = __builtin_amdgcn_mfma_f32_16x16x32_bf16(af, bf, acc2[i], 0, 0, 0);
        }
    }
    #pragma unroll
    for (int i = 0; i < 2; i++) {
        int col = (w * 2 + i) * 16 + lr;
        float bb = attend_b[col];
        #pragma unroll
        for (int r = 0; r < 4; r++)
            Ys[(lg * 4 + r) * 128 + col] = f2bf(acc2[i][r] + bb);
    }
    __syncthreads();
    *(short8*)(nbrt + (size_t)m0 * 128 + tid * 8) = *(const short8*)(Ys + tid * 8);
}

// ---------------- V1: edge logits via MFMA + softmax + gather + ELU -> ctxBf -------
// wave = one node (its 16 contiguous edges). 8 MFMAs give bond@W2b for 16e x 128ch.
__global__ __launch_bounds__(256) void k_v1_edge_agg(
    const unsigned short* __restrict__ U, const int* __restrict__ esrc,
    const float* __restrict__ bond, const unsigned short* __restrict__ BW2b,
    const float* __restrict__ attw, const float* __restrict__ attb1,
    const float* __restrict__ adst, const unsigned short* __restrict__ V,
    unsigned short* __restrict__ ctxBf)
{
    __shared__ float wS[4][16];
    __shared__ int srcS[4][16];
    const int tid = threadIdx.x, l = tid & 63, w = tid >> 6;
    const int lr = l & 15, lg = l >> 4;
    const int n = blockIdx.x * 4 + w;
    const int e0 = n * 16;

    short8 af = {};
    if (lg < 2) {
        const float* bp = bond + (size_t)(e0 + lr) * 16 + lg * 8;
        float4 b0 = *(const float4*)bp, b1 = *(const float4*)(bp + 4);
        af[0] = (short)f2bf(b0.x); af[1] = (short)f2bf(b0.y);
        af[2] = (short)f2bf(b0.z); af[3] = (short)f2bf(b0.w);
        af[4] = (short)f2bf(b1.x); af[5] = (short)f2bf(b1.y);
        af[6] = (short)f2bf(b1.z); af[7] = (short)f2bf(b1.w);
    }
    f32x4 c[8];
    #pragma unroll
    for (int t = 0; t < 8; t++) {
        short8 bf = *(const short8*)(BW2b + ((size_t)(t * 64 + l)) * 8);
        f32x4 z = {};
        c[t] = __builtin_amdgcn_mfma_f32_16x16x32_bf16(af, bf, z, 0, 0, 0);
    }
    float aw[8];
    #pragma unroll
    for (int t = 0; t < 8; t++) aw[t] = attw[128 + lr * 8 + t];

    int srcs[4];
    float s[4];
    #pragma unroll
    for (int r = 0; r < 4; r++) {
        int e = e0 + lg * 4 + r;
        int src = esrc[e];
        srcs[r] = src;
        short8 u = *(const short8*)(U + (size_t)src * 128 + lr * 8);
        float a0 = 0.f;
        #pragma unroll
        for (int t = 0; t < 8; t++) {
            float y = lrelu_(c[t][r] + bf2f((unsigned short)u[t]));
            a0 = fmaf(aw[t], y, a0);
        }
        s[r] = a0;
    }
    #pragma unroll
    for (int mk = 1; mk <= 8; mk <<= 1)
        #pragma unroll
        for (int r = 0; r < 4; r++) s[r] += __shfl_xor(s[r], mk, 16);

    // logits + softmax across the wave's 16 edges (4 per lg group, replicated in lr)
    float anode = adst[n], ab = attb1[0];
    float li[4];
    #pragma unroll
    for (int r = 0; r < 4; r++) li[r] = lrelu_(anode + ab + s[r]);
    float mx = fmaxf(fmaxf(li[0], li[1]), fmaxf(li[2], li[3]));
    mx = fmaxf(mx, __shfl_xor(mx, 16));
    mx = fmaxf(mx, __shfl_xor(mx, 32));
    float ex[4], ds = 0.f;
    #pragma unroll
    for (int r = 0; r < 4; r++) { ex[r] = __expf(li[r] - mx); ds += ex[r]; }
    ds += __shfl_xor(ds, 16);
    ds += __shfl_xor(ds, 32);
    float inv = 1.f / ds;
    if (lr == 0) {
        #pragma unroll
        for (int r = 0; r < 4; r++) {
            wS[w][lg * 4 + r] = ex[r] * inv;
            srcS[w][lg * 4 + r] = srcs[r];
        }
    }
    __syncthreads();
    // weighted gather of nbr_trans rows; 2 channels per lane
    float c0 = 0.f, c1 = 0.f;
    #pragma unroll
    for (int i = 0; i < 16; i++) {
        float wi = wS[w][i];
        int src = srcS[w][i];
        unsigned vv = *(const unsigned*)(V + (size_t)src * 128 + l * 2);
        c0 = fmaf(wi, bf2f((unsigned short)(vv & 0xffffu)), c0);
        c1 = fmaf(wi, bf2f((unsigned short)(vv >> 16)), c1);
    }
    c0 = c0 > 0.f ? c0 : __expf(c0) - 1.f;
    c1 = c1 > 0.f ? c1 : __expf(c1) - 1.f;
    unsigned o = (unsigned)f2bf(c0) | ((unsigned)f2bf(c1) << 16);
    *(unsigned*)(ctxBf + (size_t)n * 128 + l * 2) = o;
}

// ---------------- GRU (template): MODE1 aggregates ctx inline (V2 layers) ---------
// gi = ctx@wih^T, gh = h@whh^T; gates in fragment domain (no LDS re-layout).
template<int MODE>
__global__ __launch_bounds__(256) void k_gru(
    const unsigned short* __restrict__ ctxBf,
    const float* __restrict__ aD, const float* __restrict__ bS,
    const int* __restrict__ esrc, const float* __restrict__ bias1,
    const unsigned short* __restrict__ V,
    const unsigned short* __restrict__ hBf,
    const unsigned short* __restrict__ Bih, const unsigned short* __restrict__ Bhh,
    const float* __restrict__ bih, const float* __restrict__ bhh,
    const float* __restrict__ hprevF, float* __restrict__ houtF,
    unsigned short* __restrict__ houtBf)
{
    __shared__ unsigned short ctxS[16][136];
    const int tid = threadIdx.x, l = tid & 63, w = tid >> 6;
    const int lr = l & 15, lg = l >> 4;
    const int m0 = blockIdx.x * 16;

    if (MODE == 1) {
        const int t = tid >> 4, q = tid & 15;
        const int node = m0 + t;
        int srcq = esrc[node * 16 + q];
        float lg0 = lrelu_(aD[node] + bS[srcq] + bias1[0]);
        float mx = lg0;
        #pragma unroll
        for (int mk = 1; mk <= 8; mk <<= 1) mx = fmaxf(mx, __shfl_xor(mx, mk, 16));
        float ex = __expf(lg0 - mx);
        float den = ex;
        #pragma unroll
        for (int mk = 1; mk <= 8; mk <<= 1) den += __shfl_xor(den, mk, 16);
        float wq = ex / den;
        float s[8] = {};
        #pragma unroll
        for (int i = 0; i < 16; i++) {
            float wi = __shfl(wq, i, 16);
            int src = __shfl(srcq, i, 16);
            short8 vv = *(const short8*)(V + (size_t)src * 128 + q * 8);
            #pragma unroll
            for (int j = 0; j < 8; j++) s[j] = fmaf(wi, bf2f((unsigned short)vv[j]), s[j]);
        }
        short8 cv;
        #pragma unroll
        for (int j = 0; j < 8; j++) {
            float v = s[j];
            v = v > 0.f ? v : __expf(v) - 1.f;
            cv[j] = (short)f2bf(v);
        }
        *(short8*)&ctxS[t][q * 8] = cv;
        __syncthreads();
    }

    f32x4 acc[12] = {};
    #pragma unroll
    for (int ko = 0; ko < 4; ko++) {
        short8 afc;
        if (MODE == 1) afc = *(const short8*)&ctxS[lr][ko * 32 + lg * 8];
        else afc = *(const short8*)(ctxBf + (size_t)(m0 + lr) * 128 + ko * 32 + lg * 8);
        short8 afh = *(const short8*)(hBf + (size_t)(m0 + lr) * 128 + ko * 32 + lg * 8);
        #pragma unroll
        for (int i2 = 0; i2 < 6; i2++) {
            short8 bf = *(const short8*)(Bih + ((size_t)((w + 4 * i2) * 4 + ko) * 64 + l) * 8);
            acc[i2] = __builtin_amdgcn_mfma_f32_16x16x32_bf16(afc, bf, acc[i2], 0, 0, 0);
        }
        #pragma unroll
        for (int i2 = 0; i2 < 6; i2++) {
            short8 bf = *(const short8*)(Bhh + ((size_t)((w + 4 * i2) * 4 + ko) * 64 + l) * 8);
            acc[6 + i2] = __builtin_amdgcn_mfma_f32_16x16x32_bf16(afh, bf, acc[6 + i2], 0, 0, 0);
        }
    }
    // fragment-domain gates: channel c -> tile i ; c+128 -> i+2 ; c+256 -> i+4
    #pragma unroll
    for (int i = 0; i < 2; i++) {
        const int c = (w + 4 * i) * 16 + lr;
        const float br = bih[c] + bhh[c];
        const float bz = bih[c + 128] + bhh[c + 128];
        const float bin_ = bih[c + 256];
        const float bhn = bhh[c + 256];
        #pragma unroll
        for (int r = 0; r < 4; r++) {
            const int row = m0 + lg * 4 + r;
            float rg = sigmoidf_(acc[i][r] + acc[6 + i][r] + br);
            float zg = sigmoidf_(acc[i + 2][r] + acc[8 + i][r] + bz);
            float ng = tanhf_(acc[i + 4][r] + bin_ + rg * (acc[10 + i][r] + bhn));
            float hp = hprevF[(size_t)row * 128 + c];
            float ho = fmaf(zg, hp - ng, ng);
            houtF[(size_t)row * 128 + c] = ho;
            houtBf[(size_t)row * 128 + c] = f2bf(ho);
        }
    }
}

// ---------------- V2 front: nt = fc2(h); a,b node dots vs v2_fc1_w ----------------
__global__ __launch_bounds__(256) void k_v2_front(
    const unsigned short* __restrict__ hBf, const unsigned short* __restrict__ Bfc2,
    const float* __restrict__ fc2b, const float* __restrict__ w2att,
    unsigned short* __restrict__ nt, float* __restrict__ aD, float* __restrict__ bS)
{
    __shared__ unsigned short Ys[16 * 128];
    const int tid = threadIdx.x, l = tid & 63, w = tid >> 6;
    const int lr = l & 15, lg = l >> 4;
    const int m0 = blockIdx.x * 16;
    {
        int row = tid >> 4, q = tid & 15;
        short8 hv = *(const short8*)(hBf + (size_t)(m0 + row) * 128 + q * 8);
        float pa = 0.f, pb = 0.f;
        #pragma unroll
        for (int j = 0; j < 8; j++) {
            float x = bf2f((unsigned short)hv[j]);
            pa = fmaf(x, w2att[q * 8 + j], pa);
            pb = fmaf(x, w2att[128 + q * 8 + j], pb);
        }
        #pragma unroll
        for (int m = 1; m <= 8; m <<= 1) {
            pa += __shfl_xor(pa, m, 16);
            pb += __shfl_xor(pb, m, 16);
        }
        if (q == 0) { aD[m0 + row] = pa; bS[m0 + row] = pb; }
    }
    f32x4 acc[2] = {};
    const unsigned short* Arow = hBf + (size_t)(m0 + lr) * 128 + lg * 8;
    #pragma unroll
    for (int ko = 0; ko < 4; ko++) {
        short8 af = *(const short8*)(Arow + ko * 32);
        #pragma unroll
        for (int i = 0; i < 2; i++) {
            int t = w * 2 + i;
            short8 bf = *(const short8*)(Bfc2 + ((size_t)(t * 4 + ko) * 64 + l) * 8);
            acc[i] = __builtin_amdgcn_mfma_f32_16x16x32_bf16(af, bf, acc[i], 0, 0, 0);
        }
    }
    #pragma unroll
    for (int i = 0; i < 2; i++) {
        int col = (w * 2 + i) * 16 + lr;
        float bb = fc2b[col];
        #pragma unroll
        for (int r = 0; r < 4; r++)
            Ys[(lg * 4 + r) * 128 + col] = f2bf(acc[i][r] + bb);
    }
    __syncthreads();
    *(short8*)(nt + (size_t)m0 * 128 + tid * 8) = *(const short8*)(Ys + tid * 8);
}

// ---------------- final: avg + lin + gelu ----------------
__global__ __launch_bounds__(256) void k_final(
    const float* __restrict__ a0, const float* __restrict__ a1, const float* __restrict__ a2,
    const unsigned short* __restrict__ Blin, const float* __restrict__ linb,
    float* __restrict__ avgOut, float* __restrict__ out)
{
    __shared__ unsigned short Ys[16 * 136];
    const int tid = threadIdx.x, l = tid & 63, w = tid >> 6;
    const int lr = l & 15, lg = l >> 4;
    const int m0 = blockIdx.x * 16;
    {
        int row = tid >> 4, q = tid & 15;
        size_t base = (size_t)(m0 + row) * 128 + q * 8;
        float v[8];
        #pragma unroll
        for (int h = 0; h < 2; h++) {
            float4 x0 = *(const float4*)(a0 + base + h * 4);
            float4 x1 = *(const float4*)(a1 + base + h * 4);
            float4 x2 = *(const float4*)(a2 + base + h * 4);
            v[h * 4 + 0] = (x0.x + x1.x + x2.x) * (1.f / 3.f);
            v[h * 4 + 1] = (x0.y + x1.y + x2.y) * (1.f / 3.f);
            v[h * 4 + 2] = (x0.z + x1.z + x2.z) * (1.f / 3.f);
            v[h * 4 + 3] = (x0.w + x1.w + x2.w) * (1.f / 3.f);
        }
        *(float4*)(avgOut + base) = *(float4*)v;
        *(float4*)(avgOut + base + 4) = *(float4*)(v + 4);
        #pragma unroll
        for (int j = 0; j < 8; j++) Ys[row * 136 + q * 8 + j] = f2bf(v[j]);
    }
    __syncthreads();
    f32x4 acc[2] = {};
    #pragma unroll
    for (int ko = 0; ko < 4; ko++) {
        short8 af = *(const short8*)(Ys + lr * 136 + ko * 32 + lg * 8);
        #pragma unroll
        for (int i = 0; i < 2; i++) {
            int t = w * 2 + i;
            short8 bf = *(const short8*)(Blin + ((size_t)(t * 4 + ko) * 64 + l) * 8);
            acc[i] = __builtin_amdgcn_mfma_f32_16x16x32_bf16(af, bf, acc[i], 0, 0, 0);
        }
    }
    #pragma unroll
    for (int i = 0; i < 2; i++) {
        int col = (w * 2 + i) * 16 + lr;
        float bb = linb[col];
        #pragma unroll
        for (int r = 0; r < 4; r++) {
            float vv = acc[i][r] + bb;
            vv = 0.5f * vv * (1.f + erff(vv * 0.70710678118654752f));
            out[(size_t)(m0 + lg * 4 + r) * 128 + col] = vv;
        }
    }
}

extern "C" void kernel_launch(void* const* d_in, const int* in_sizes, int n_in,
                              void* d_out, int out_size, void* d_ws, size_t ws_size,
                              hipStream_t stream) {
    const float* atom     = (const float*)d_in[0];
    const int*   esrc     = (const int*)d_in[1];
    const float* bond     = (const float*)d_in[3];
    const float* fc1_w    = (const float*)d_in[4];
    const float* fc1_b    = (const float*)d_in[5];
    const float* fc2_w    = (const float*)d_in[6];
    const float* fc2_b    = (const float*)d_in[7];
    const float* att_w    = (const float*)d_in[8];
    const float* att_b    = (const float*)d_in[9];
    const float* attend_w = (const float*)d_in[10];
    const float* attend_b = (const float*)d_in[11];
    const float* gih1     = (const float*)d_in[12];
    const float* ghh1     = (const float*)d_in[13];
    const float* bih1     = (const float*)d_in[14];
    const float* bhh1     = (const float*)d_in[15];
    const float* fc1v2_w  = (const float*)d_in[16];
    const float* fc1v2_b  = (const float*)d_in[17];
    const float* fc2v2_w  = (const float*)d_in[18];
    const float* fc2v2_b  = (const float*)d_in[19];
    const float* gih2     = (const float*)d_in[20];
    const float* ghh2     = (const float*)d_in[21];
    const float* bih2     = (const float*)d_in[22];
    const float* bhh2     = (const float*)d_in[23];
    const float* lin_w    = (const float*)d_in[24];
    const float* lin_b    = (const float*)d_in[25];

    char* wsb = (char*)d_ws;
    size_t off = 0;
    auto allocB = [&](size_t bytes) {
        size_t o = off; off = (off + bytes + 255) & ~(size_t)255; return o;
    };
    unsigned short* Bfc1   = (unsigned short*)(wsb + allocB(128 * 128 * 2));
    unsigned short* Batt   = (unsigned short*)(wsb + allocB(128 * 128 * 2));
    unsigned short* BW2a   = (unsigned short*)(wsb + allocB(128 * 128 * 2));
    unsigned short* BW2b   = (unsigned short*)(wsb + allocB(512 * 8 * 2));
    unsigned short* Bgih1  = (unsigned short*)(wsb + allocB(384 * 128 * 2));
    unsigned short* Bghh1  = (unsigned short*)(wsb + allocB(384 * 128 * 2));
    unsigned short* Bfc2v2 = (unsigned short*)(wsb + allocB(128 * 128 * 2));
    unsigned short* Bgih2  = (unsigned short*)(wsb + allocB(384 * 128 * 2));
    unsigned short* Bghh2  = (unsigned short*)(wsb + allocB(384 * 128 * 2));
    unsigned short* Blin   = (unsigned short*)(wsb + allocB(128 * 128 * 2));
    unsigned short* naBf   = (unsigned short*)(wsb + allocB((size_t)NN * 128 * 2));
    unsigned short* Ubf    = (unsigned short*)(wsb + allocB((size_t)NN * 128 * 2));
    unsigned short* nbrt   = (unsigned short*)(wsb + allocB((size_t)NN * 128 * 2));
    unsigned short* ctxBf  = (unsigned short*)(wsb + allocB((size_t)NN * 128 * 2));
    unsigned short* h1Bf   = (unsigned short*)(wsb + allocB((size_t)NN * 128 * 2));
    unsigned short* h2Bf   = (unsigned short*)(wsb + allocB((size_t)NN * 128 * 2));
    float* adst = (float*)(wsb + allocB((size_t)NN * 4));
    float* bsrc = (float*)(wsb + allocB((size_t)NN * 4));
    (void)ws_size;

    float* out0 = (float*)d_out;
    float* as0  = out0 + (size_t)NN * 128;
    float* as1  = as0 + (size_t)NN * 128;
    float* as2  = as1 + (size_t)NN * 128;
    float* g0   = out0 + (size_t)4 * NN * 128;
    float* avg  = out0 + (size_t)5 * NN * 128;

    PackArgs pa;
    pa.d[0] = { fc1_w,    Bfc1,   128, 128 };
    pa.d[1] = { attend_w, Batt,   128, 128 };
    pa.d[2] = { fc2_w,    BW2a,   128, 144 };
    pa.d[3] = { gih1,     Bgih1,  384, 128 };
    pa.d[4] = { ghh1,     Bghh1,  384, 128 };
    pa.d[5] = { fc2v2_w,  Bfc2v2, 128, 128 };
    pa.d[6] = { gih2,     Bgih2,  384, 128 };
    pa.d[7] = { ghh2,     Bghh2,  384, 128 };
    pa.d[8] = { lin_w,    Blin,   128, 128 };
    k_pack<<<dim3(24, 9), 256, 0, stream>>>(pa);
    k_pack_w2b<<<2, 256, 0, stream>>>(fc2_w, BW2b);

    const int GB = NN / 16;  // 1250

    // ---- V1 ----
    k_v1_front<<<GB, 256, 0, stream>>>(atom, Bfc1, BW2a, Batt, fc1_b, fc2_b,
                                       attend_b, att_w, g0, naBf, Ubf, nbrt, adst);
    k_v1_edge_agg<<<NN / 4, 256, 0, stream>>>(Ubf, esrc, bond, BW2b, att_w, att_b,
                                              adst, nbrt, ctxBf);
    k_gru<0><<<GB, 256, 0, stream>>>(ctxBf, nullptr, nullptr, nullptr, nullptr, nullptr,
                                     naBf, Bgih1, Bghh1, bih1, bhh1, g0, as0, h1Bf);

    // ---- V2 x2 ----
    const unsigned short* hBfIn = h1Bf;
    const float* hFIn = as0;
    unsigned short* hBfOut[2] = { h2Bf, h1Bf };
    float* hFOut[2] = { as1, as2 };
    for (int lyr = 0; lyr < 2; lyr++) {
        k_v2_front<<<GB, 256, 0, stream>>>(hBfIn, Bfc2v2, fc2v2_b, fc1v2_w,
                                           nbrt, adst, bsrc);
        k_gru<1><<<GB, 256, 0, stream>>>(nullptr, adst, bsrc, esrc, fc1v2_b, nbrt,
                                         hBfIn, Bgih2, Bghh2, bih2, bhh2,
                                         hFIn, hFOut[lyr], hBfOut[lyr]);
        hBfIn = hBfOut[lyr];
        hFIn = hFOut[lyr];
    }

    // ---- final ----
    k_final<<<GB, 256, 0, stream>>>(as0, as1, as2, Blin, lin_b, avg, out0);
}